// Round 1
// baseline (174.000 us; speedup 1.0000x reference)
//
#include <hip/hip_runtime.h>

// AugmentShallow: factorized point-MLP + gather-mean + output GEMM (fp32)
//
// Key identity: the per-(b,n,k) MLP depends only on the gathered point j =
// knn_idx[b,n,k], so compute t[b,j] = MLP(x[b,j]) once per point (kernel 1),
// then m[b,n] = mean_k t[b, idx[b,n,k]] and out = W2 m + b2 (kernel 2).
// This cuts FLOPs 12x vs the reference formulation.

constexpr int NB   = 8;
constexpr int NN   = 8192;
constexpr int NK   = 12;
constexpr int CH   = 128;
constexpr int COUT = 256;
constexpr int PTS  = 64;    // points per block

// ---------------------------------------------------------------------------
// Kernel 1: pointwise 3-128-128-128 MLP over all B*N points.
// Block: 256 threads, 64 points. h kept transposed [ch][pt] in LDS; weights
// streamed through an 8-wide k-panel in LDS. Thread tile: 4 pts x 8 ch.
// ---------------------------------------------------------------------------

template <bool TO_GLOBAL>
__device__ __forceinline__ void layer128(
    const float (*__restrict__ hin)[PTS], float (*__restrict__ hout)[PTS],
    float (*__restrict__ wpan)[CH],
    const float* __restrict__ W, const float* __restrict__ bias,
    float* __restrict__ gout, long prow_base,
    int tid, int p0, int c0)
{
    float acc[4][8];
#pragma unroll
    for (int j = 0; j < 8; ++j) {
        const float bb = bias[c0 + j];
#pragma unroll
        for (int i = 0; i < 4; ++i) acc[i][j] = bb;
    }

    const int cw = tid >> 1;     // W row this thread stages (0..127)
    const int half = tid & 1;    // which 4-wide half of the 8-k panel
    const float* wsrc = W + (long)cw * CH + half * 4;

#pragma unroll 1
    for (int kp = 0; kp < 16; ++kp) {
        __syncthreads();  // protect wpan reuse (and layer-boundary h hazard)
        const float4 wv = *(const float4*)(wsrc + kp * 8);
        wpan[half * 4 + 0][cw] = wv.x;
        wpan[half * 4 + 1][cw] = wv.y;
        wpan[half * 4 + 2][cw] = wv.z;
        wpan[half * 4 + 3][cw] = wv.w;
        __syncthreads();
#pragma unroll
        for (int kk = 0; kk < 8; ++kk) {
            const float4 hv = *(const float4*)&hin[kp * 8 + kk][p0];
            const float4 wa = *(const float4*)&wpan[kk][c0];
            const float4 wb = *(const float4*)&wpan[kk][c0 + 4];
            const float hr[4] = {hv.x, hv.y, hv.z, hv.w};
            const float wr[8] = {wa.x, wa.y, wa.z, wa.w, wb.x, wb.y, wb.z, wb.w};
#pragma unroll
            for (int i = 0; i < 4; ++i)
#pragma unroll
                for (int j = 0; j < 8; ++j)
                    acc[i][j] = fmaf(hr[i], wr[j], acc[i][j]);
        }
    }

    if (TO_GLOBAL) {
        // relu + store t[p][c0..c0+7]
#pragma unroll
        for (int i = 0; i < 4; ++i) {
            float4 v0, v1;
            v0.x = fmaxf(acc[i][0], 0.f); v0.y = fmaxf(acc[i][1], 0.f);
            v0.z = fmaxf(acc[i][2], 0.f); v0.w = fmaxf(acc[i][3], 0.f);
            v1.x = fmaxf(acc[i][4], 0.f); v1.y = fmaxf(acc[i][5], 0.f);
            v1.z = fmaxf(acc[i][6], 0.f); v1.w = fmaxf(acc[i][7], 0.f);
            float* op = gout + (prow_base + p0 + i) * (long)CH + c0;
            *(float4*)(op + 0) = v0;
            *(float4*)(op + 4) = v1;
        }
    } else {
        // relu + store transposed h[c][p0..p0+3]
#pragma unroll
        for (int j = 0; j < 8; ++j) {
            float4 v;
            v.x = fmaxf(acc[0][j], 0.f);
            v.y = fmaxf(acc[1][j], 0.f);
            v.z = fmaxf(acc[2][j], 0.f);
            v.w = fmaxf(acc[3][j], 0.f);
            *(float4*)&hout[c0 + j][p0] = v;
        }
    }
}

__global__ __launch_bounds__(256, 2) void k_pointmlp(
    const float* __restrict__ x,
    const float* __restrict__ W1, const float* __restrict__ b1,
    const float* __restrict__ Wc0, const float* __restrict__ bc0,
    const float* __restrict__ Wc1, const float* __restrict__ bc1,
    float* __restrict__ t)
{
    __shared__ float hA[CH][PTS];     // 32 KiB
    __shared__ float hB[CH][PTS];     // 32 KiB
    __shared__ float wpan[8][CH];     //  4 KiB

    const int tid = threadIdx.x;
    const int ptg = tid & 15, chg = tid >> 4;
    const int p0 = ptg * 4, c0 = chg * 8;
    const long pblk = (long)blockIdx.x * PTS;

    // ---- layer 1: h1 = W1 @ x + b1 (no relu), write transposed to hA ----
    {
        const float* xp = x + (pblk + p0) * 3;
        const float4 xa = *(const float4*)(xp + 0);
        const float4 xb = *(const float4*)(xp + 4);
        const float4 xc = *(const float4*)(xp + 8);
        const float X0[3] = {xa.x, xa.y, xa.z};
        const float X1[3] = {xa.w, xb.x, xb.y};
        const float X2[3] = {xb.z, xb.w, xc.x};
        const float X3[3] = {xc.y, xc.z, xc.w};
#pragma unroll
        for (int j = 0; j < 8; ++j) {
            const int c = c0 + j;
            const float w0 = W1[c * 3 + 0], w1 = W1[c * 3 + 1], w2 = W1[c * 3 + 2];
            const float bb = b1[c];
            float4 v;
            v.x = fmaf(w2, X0[2], fmaf(w1, X0[1], fmaf(w0, X0[0], bb)));
            v.y = fmaf(w2, X1[2], fmaf(w1, X1[1], fmaf(w0, X1[0], bb)));
            v.z = fmaf(w2, X2[2], fmaf(w1, X2[1], fmaf(w0, X2[0], bb)));
            v.w = fmaf(w2, X3[2], fmaf(w1, X3[1], fmaf(w0, X3[0], bb)));
            *(float4*)&hA[c][p0] = v;
        }
    }
    // (layer2's first __syncthreads orders hA writes vs reads)

    // ---- layer 2: hB = relu(Wc0 @ hA + bc0) ----
    layer128<false>(hA, hB, wpan, Wc0, bc0, nullptr, 0, tid, p0, c0);
    // ---- layer 3: t = relu(Wc1 @ hB + bc1), direct to global ----
    layer128<true>(hB, nullptr, wpan, Wc1, bc1, t, pblk, tid, p0, c0);
}

// ---------------------------------------------------------------------------
// Kernel 2: gather-mean over K=12 neighbors + out = W2 @ m + b2.
// Block: 256 threads, 64 points of one batch. b = blockIdx.x & 7 pins each
// batch's 4 MB t-slice to one XCD's L2. Thread tile phase 2: 4 pts x 16 out.
// ---------------------------------------------------------------------------

__global__ __launch_bounds__(256, 2) void k_gather_out(
    const int* __restrict__ knn,
    const float* __restrict__ t,
    const float* __restrict__ W2, const float* __restrict__ b2,
    float* __restrict__ out)
{
    __shared__ float mT[CH][PTS];       // 32 KiB, m transposed [ch][pt]
    __shared__ float w2pan[8][COUT];    //  8 KiB

    const int tid = threadIdx.x;
    const int b = blockIdx.x & 7;          // batch -> XCD locality
    const int nblk = blockIdx.x >> 3;
    const long pbase = (long)b * NN + (long)nblk * PTS;  // flat point base

    // ---- phase 1: m[pt] = mean_k t[b, idx[k]] ----
    {
        const int pt = tid >> 2;
        const int c0 = (tid & 3) * 32;
        const int* ip = knn + (pbase + pt) * NK;
        const int4 ia = *(const int4*)(ip + 0);
        const int4 ib = *(const int4*)(ip + 4);
        const int4 ic = *(const int4*)(ip + 8);
        const int idxs[12] = {ia.x, ia.y, ia.z, ia.w,
                              ib.x, ib.y, ib.z, ib.w,
                              ic.x, ic.y, ic.z, ic.w};
        float acc[32];
#pragma unroll
        for (int c = 0; c < 32; ++c) acc[c] = 0.f;
#pragma unroll
        for (int k = 0; k < NK; ++k) {
            const float* tp = t + ((long)b * NN + idxs[k]) * CH + c0;
#pragma unroll
            for (int q = 0; q < 8; ++q) {
                const float4 v = *(const float4*)(tp + q * 4);
                acc[q * 4 + 0] += v.x;
                acc[q * 4 + 1] += v.y;
                acc[q * 4 + 2] += v.z;
                acc[q * 4 + 3] += v.w;
            }
        }
        const float s = 1.f / 12.f;
#pragma unroll
        for (int c = 0; c < 32; ++c) mT[c0 + c][pt] = acc[c] * s;
    }

    // ---- phase 2: out = W2 @ m + b2 ----
    const int ptg = tid & 15, og = tid >> 4;
    const int p0 = ptg * 4, o0 = og * 16;
    float acc[4][16];
#pragma unroll
    for (int j = 0; j < 16; ++j) {
        const float bb = b2[o0 + j];
#pragma unroll
        for (int i = 0; i < 4; ++i) acc[i][j] = bb;
    }
    const float* w2src = W2 + (long)tid * CH;
#pragma unroll 1
    for (int kp = 0; kp < 16; ++kp) {
        __syncthreads();   // kp=0: also orders mT writes vs reads
        const float4 wa = *(const float4*)(w2src + kp * 8);
        const float4 wb = *(const float4*)(w2src + kp * 8 + 4);
        w2pan[0][tid] = wa.x;
        w2pan[1][tid] = wa.y;
        w2pan[2][tid] = wa.z;
        w2pan[3][tid] = wa.w;
        w2pan[4][tid] = wb.x;
        w2pan[5][tid] = wb.y;
        w2pan[6][tid] = wb.z;
        w2pan[7][tid] = wb.w;
        __syncthreads();
#pragma unroll
        for (int kk = 0; kk < 8; ++kk) {
            const float4 hv = *(const float4*)&mT[kp * 8 + kk][p0];
            const float hr[4] = {hv.x, hv.y, hv.z, hv.w};
            const float4 q0 = *(const float4*)&w2pan[kk][o0];
            const float4 q1 = *(const float4*)&w2pan[kk][o0 + 4];
            const float4 q2 = *(const float4*)&w2pan[kk][o0 + 8];
            const float4 q3 = *(const float4*)&w2pan[kk][o0 + 12];
            const float wr[16] = {q0.x, q0.y, q0.z, q0.w, q1.x, q1.y, q1.z, q1.w,
                                  q2.x, q2.y, q2.z, q2.w, q3.x, q3.y, q3.z, q3.w};
#pragma unroll
            for (int i = 0; i < 4; ++i)
#pragma unroll
                for (int j = 0; j < 16; ++j)
                    acc[i][j] = fmaf(hr[i], wr[j], acc[i][j]);
        }
    }

    // ---- store out[b, n, 0..255] (no activation on final layer) ----
#pragma unroll
    for (int i = 0; i < 4; ++i) {
        float* op = out + (pbase + p0 + i) * (long)COUT + o0;
        float4 v0 = {acc[i][0], acc[i][1], acc[i][2], acc[i][3]};
        float4 v1 = {acc[i][4], acc[i][5], acc[i][6], acc[i][7]};
        float4 v2 = {acc[i][8], acc[i][9], acc[i][10], acc[i][11]};
        float4 v3 = {acc[i][12], acc[i][13], acc[i][14], acc[i][15]};
        *(float4*)(op + 0) = v0;
        *(float4*)(op + 4) = v1;
        *(float4*)(op + 8) = v2;
        *(float4*)(op + 12) = v3;
    }
}

// ---------------------------------------------------------------------------

extern "C" void kernel_launch(void* const* d_in, const int* in_sizes, int n_in,
                              void* d_out, int out_size, void* d_ws, size_t ws_size,
                              hipStream_t stream)
{
    const float* x   = (const float*)d_in[0];
    const int*   knn = (const int*)d_in[1];
    const float* W1  = (const float*)d_in[2];
    const float* b1  = (const float*)d_in[3];
    const float* Wc0 = (const float*)d_in[4];
    const float* bc0 = (const float*)d_in[5];
    const float* Wc1 = (const float*)d_in[6];
    const float* bc1 = (const float*)d_in[7];
    const float* W2  = (const float*)d_in[8];
    const float* b2  = (const float*)d_in[9];
    float* out = (float*)d_out;
    float* t   = (float*)d_ws;   // needs B*N*128*4 = 32 MiB scratch

    // kernel 1: 65536 points / 64 per block
    k_pointmlp<<<dim3(1024), dim3(256), 0, stream>>>(x, W1, b1, Wc0, bc0, Wc1, bc1, t);
    // kernel 2: 8 batches x 128 n-blocks; b = blockIdx & 7 for XCD locality
    k_gather_out<<<dim3(1024), dim3(256), 0, stream>>>(knn, t, W2, b2, out);
}

// Round 2
// 119.292 us; speedup vs baseline: 1.4586x; 1.4586x over previous
//
#include <hip/hip_runtime.h>
#include <hip/hip_fp16.h>

// AugmentShallow, round 2: MFMA bf16x3-split pipeline.
//
// Factorization (round 1): t[b,j] = MLP(x[b,j]) per point; m = mean_k gather(t);
// out = W2 m + b2. All K=128 GEMMs now run on matrix cores via the bf16 hi/lo
// split (D = Ah*Bh + Ah*Bl + Al*Bh, fp32 accum -> ~2^-16 rel error).
//
// No __syncthreads anywhere: every wave reads only the LDS rows its own
// lanes wrote (points are wave-local). LDS tiles are XOR-swizzled
// (chunk ^ (pt&7)) to kill the stride-256B bank conflict on ds_read_b128.
//
// ws layout: [0,16MB) t as fp16 [65536][128]; [16MB, +256KB) split weights.

typedef __attribute__((ext_vector_type(8))) short     bf16x8;
typedef __attribute__((ext_vector_type(4))) short     s16x4;
typedef __attribute__((ext_vector_type(4))) float     f32x4;
typedef __attribute__((ext_vector_type(8))) _Float16  f16x8;
typedef __attribute__((ext_vector_type(4))) _Float16  f16x4;

#define MFMA16 __builtin_amdgcn_mfma_f32_16x16x32_bf16

__device__ __forceinline__ unsigned short bf16_rne(float f) {
    unsigned u = __float_as_uint(f);
    return (unsigned short)((u + 0x7fffu + ((u >> 16) & 1u)) >> 16);
}
__device__ __forceinline__ void bsplit(float f, unsigned short& h, unsigned short& l) {
    h = bf16_rne(f);
    l = bf16_rne(f - __uint_as_float((unsigned)h << 16));
}

// ---------------------------------------------------------------------------
// Prep: split Wc0/Wc1/W2 into bf16 hi/lo planes in ws.
// ushort offsets in wb: Wc0h 0, Wc0l 16384, Wc1h 32768, Wc1l 49152,
//                       W2h 65536, W2l 98304.
// ---------------------------------------------------------------------------
__global__ void k_prep(const float* __restrict__ Wc0, const float* __restrict__ Wc1,
                       const float* __restrict__ W2, unsigned short* __restrict__ wb)
{
    const int i = blockIdx.x * 256 + threadIdx.x;   // 0..65535
    float v; unsigned short *ph, *pl;
    if (i < 16384)      {               v = Wc0[i]; ph = wb + i;         pl = wb + 16384 + i; }
    else if (i < 32768) { int j = i - 16384; v = Wc1[j]; ph = wb + 32768 + j; pl = wb + 49152 + j; }
    else                { int j = i - 32768; v = W2[j];  ph = wb + 65536 + j; pl = wb + 98304 + j; }
    unsigned short h, l; bsplit(v, h, l);
    *ph = h; *pl = l;
}

// ---------------------------------------------------------------------------
// Kernel 1: point MLP. Block = 256 thr (4 waves), 128 points.
// Wave w owns pts [32w, 32w+32): 2 pt-tiles x 8 ch-tiles, MFMA 16x16x32.
// ---------------------------------------------------------------------------
__global__ __launch_bounds__(256) void k_mlp(
    const float* __restrict__ x,
    const float* __restrict__ W1, const float* __restrict__ b1,
    const float* __restrict__ bc0, const float* __restrict__ bc1,
    const unsigned short* __restrict__ wb,
    _Float16* __restrict__ t)
{
    __shared__ __align__(16) unsigned short hTh[128 * 128];  // 32 KiB hi plane
    __shared__ __align__(16) unsigned short hTl[128 * 128];  // 32 KiB lo plane

    const int tid = threadIdx.x;
    const int bid = blockIdx.x;
    const int lb  = (bid & 7) * 64 + (bid >> 3);   // XCD-pinned: batch = lb/64 = bid&7
    const long pblk = (long)lb * 128;

    // ---- layer 1 (fp32 VALU, K=3): pt = tid>>1, 64-ch half ----
    {
        const int pt  = tid >> 1;
        const int ch0 = (tid & 1) * 64;
        const float* xp = x + (pblk + pt) * 3;
        const float x0 = xp[0], x1 = xp[1], x2 = xp[2];
        const int p7 = pt & 7;
#pragma unroll
        for (int q = 0; q < 8; ++q) {
            bf16x8 vh, vl;
#pragma unroll
            for (int j = 0; j < 8; ++j) {
                const int c = ch0 + q * 8 + j;
                float v = b1[c];
                v = fmaf(W1[c * 3 + 0], x0, v);
                v = fmaf(W1[c * 3 + 1], x1, v);
                v = fmaf(W1[c * 3 + 2], x2, v);
                unsigned short h, l; bsplit(v, h, l);
                vh[j] = (short)h; vl[j] = (short)l;
            }
            const int chunk = (ch0 >> 3) + q;
            const int sidx  = pt * 128 + ((chunk ^ p7) << 3);
            *(bf16x8*)&hTh[sidx] = vh;
            *(bf16x8*)&hTl[sidx] = vl;
        }
    }
    // No barrier: wave w's lanes wrote exactly the pt rows wave w reads below.

    const int lane = tid & 63;
    const int w  = tid >> 6;
    const int fr = lane & 15;
    const int g  = lane >> 4;

    const unsigned short* Whp[2] = { wb,          wb + 32768 };
    const unsigned short* Wlp[2] = { wb + 16384,  wb + 49152 };
    const float*          bp2[2] = { bc0, bc1 };

    bf16x8 Bh[2][4], Bl[2][4];
#pragma unroll
    for (int u = 0; u < 2; ++u) {
        const int pt = w * 32 + u * 16 + fr;
        const int p7 = pt & 7;
#pragma unroll
        for (int c = 0; c < 4; ++c) {
            const int sidx = pt * 128 + (((4 * c + g) ^ p7) << 3);
            Bh[u][c] = *(const bf16x8*)&hTh[sidx];
            Bl[u][c] = *(const bf16x8*)&hTl[sidx];
        }
    }

#pragma unroll
    for (int layer = 0; layer < 2; ++layer) {
        const unsigned short* wh = Whp[layer];
        const unsigned short* wl = Wlp[layer];
        const float* bp = bp2[layer];
#pragma unroll 2
        for (int t8 = 0; t8 < 8; ++t8) {
            const int row = t8 * 16 + fr;
            bf16x8 ah[4], al[4];
#pragma unroll
            for (int c = 0; c < 4; ++c) {
                ah[c] = *(const bf16x8*)(wh + row * 128 + 32 * c + g * 8);
                al[c] = *(const bf16x8*)(wl + row * 128 + 32 * c + g * 8);
            }
            const float4 bv = *(const float4*)(bp + t8 * 16 + g * 4);
            f32x4 a0 = { bv.x, bv.y, bv.z, bv.w };
            f32x4 a1 = a0;
#pragma unroll
            for (int c = 0; c < 4; ++c) {
                a0 = MFMA16(ah[c], Bh[0][c], a0, 0, 0, 0);
                a1 = MFMA16(ah[c], Bh[1][c], a1, 0, 0, 0);
                a0 = MFMA16(ah[c], Bl[0][c], a0, 0, 0, 0);
                a1 = MFMA16(ah[c], Bl[1][c], a1, 0, 0, 0);
                a0 = MFMA16(al[c], Bh[0][c], a0, 0, 0, 0);
                a1 = MFMA16(al[c], Bh[1][c], a1, 0, 0, 0);
            }
            if (layer == 0) {
                // relu + split, write h2 back over hT (B1 already in regs)
#pragma unroll
                for (int u = 0; u < 2; ++u) {
                    const f32x4 av = u ? a1 : a0;
                    const int pt = w * 32 + u * 16 + fr;
                    const int p7 = pt & 7;
                    s16x4 sh, sl;
#pragma unroll
                    for (int r = 0; r < 4; ++r) {
                        const float v = fmaxf(av[r], 0.f);
                        unsigned short h, l; bsplit(v, h, l);
                        sh[r] = (short)h; sl[r] = (short)l;
                    }
                    const int chunk = 2 * t8 + (g >> 1);
                    const int sidx  = pt * 128 + ((chunk ^ p7) << 3) + (g & 1) * 4;
                    *(s16x4*)&hTh[sidx] = sh;
                    *(s16x4*)&hTl[sidx] = sl;
                }
            } else {
                // relu + fp16 store to t
#pragma unroll
                for (int u = 0; u < 2; ++u) {
                    const f32x4 av = u ? a1 : a0;
                    const long pt = pblk + w * 32 + u * 16 + fr;
                    f16x4 o;
#pragma unroll
                    for (int r = 0; r < 4; ++r) o[r] = (_Float16)fmaxf(av[r], 0.f);
                    *(f16x4*)&t[pt * 128 + t8 * 16 + g * 4] = o;
                }
            }
        }
        if (layer == 0) {
            // reload B frags = h2 (written above by this same wave)
#pragma unroll
            for (int u = 0; u < 2; ++u) {
                const int pt = w * 32 + u * 16 + fr;
                const int p7 = pt & 7;
#pragma unroll
                for (int c = 0; c < 4; ++c) {
                    const int sidx = pt * 128 + (((4 * c + g) ^ p7) << 3);
                    Bh[u][c] = *(const bf16x8*)&hTh[sidx];
                    Bl[u][c] = *(const bf16x8*)&hTl[sidx];
                }
            }
        }
    }
}

// ---------------------------------------------------------------------------
// Kernel 2: gather-mean (fp16 t, fp32 accum) + W2 GEMM via MFMA.
// Block = 256 thr, 128 points of one batch; b = bid&7 pins batch to XCD.
// ---------------------------------------------------------------------------
__global__ __launch_bounds__(256) void k_out(
    const int* __restrict__ knn,
    const _Float16* __restrict__ t,
    const unsigned short* __restrict__ wb,
    const float* __restrict__ b2,
    float* __restrict__ out)
{
    __shared__ __align__(16) unsigned short mTh[128 * 128];
    __shared__ __align__(16) unsigned short mTl[128 * 128];

    const int tid  = threadIdx.x;
    const int b    = blockIdx.x & 7;
    const int nblk = blockIdx.x >> 3;
    const long pbase = (long)b * 8192 + (long)nblk * 128;

    // ---- gather-mean: pt = tid>>1, 64-ch half ----
    {
        const int pt  = tid >> 1;
        const int ch0 = (tid & 1) * 64;
        const int* ip = knn + (pbase + pt) * 12;
        int idx[12];
        *(int4*)&idx[0] = *(const int4*)(ip + 0);
        *(int4*)&idx[4] = *(const int4*)(ip + 4);
        *(int4*)&idx[8] = *(const int4*)(ip + 8);
        float acc[64];
#pragma unroll
        for (int c = 0; c < 64; ++c) acc[c] = 0.f;
#pragma unroll
        for (int k = 0; k < 12; ++k) {
            const _Float16* tp = t + ((long)b * 8192 + idx[k]) * 128 + ch0;
#pragma unroll
            for (int q = 0; q < 8; ++q) {
                const f16x8 v = *(const f16x8*)(tp + q * 8);
#pragma unroll
                for (int j = 0; j < 8; ++j) acc[q * 8 + j] += (float)v[j];
            }
        }
        const int p7 = pt & 7;
#pragma unroll
        for (int q = 0; q < 8; ++q) {
            bf16x8 vh, vl;
#pragma unroll
            for (int j = 0; j < 8; ++j) {
                unsigned short h, l;
                bsplit(acc[q * 8 + j] * (1.f / 12.f), h, l);
                vh[j] = (short)h; vl[j] = (short)l;
            }
            const int chunk = (ch0 >> 3) + q;
            const int sidx  = pt * 128 + ((chunk ^ p7) << 3);
            *(bf16x8*)&mTh[sidx] = vh;
            *(bf16x8*)&mTl[sidx] = vl;
        }
    }
    // No barrier: wave-local pt rows.

    const int lane = tid & 63;
    const int w  = tid >> 6;
    const int fr = lane & 15;
    const int g  = lane >> 4;
    const unsigned short* w2h = wb + 65536;
    const unsigned short* w2l = wb + 98304;

    bf16x8 Bh[2][4], Bl[2][4];
#pragma unroll
    for (int u = 0; u < 2; ++u) {
        const int pt = w * 32 + u * 16 + fr;
        const int p7 = pt & 7;
#pragma unroll
        for (int c = 0; c < 4; ++c) {
            const int sidx = pt * 128 + (((4 * c + g) ^ p7) << 3);
            Bh[u][c] = *(const bf16x8*)&mTh[sidx];
            Bl[u][c] = *(const bf16x8*)&mTl[sidx];
        }
    }

#pragma unroll 2
    for (int t16 = 0; t16 < 16; ++t16) {
        const int row = t16 * 16 + fr;
        bf16x8 ah[4], al[4];
#pragma unroll
        for (int c = 0; c < 4; ++c) {
            ah[c] = *(const bf16x8*)(w2h + row * 128 + 32 * c + g * 8);
            al[c] = *(const bf16x8*)(w2l + row * 128 + 32 * c + g * 8);
        }
        const float4 bv = *(const float4*)(b2 + t16 * 16 + g * 4);
        f32x4 a0 = { bv.x, bv.y, bv.z, bv.w };
        f32x4 a1 = a0;
#pragma unroll
        for (int c = 0; c < 4; ++c) {
            a0 = MFMA16(ah[c], Bh[0][c], a0, 0, 0, 0);
            a1 = MFMA16(ah[c], Bh[1][c], a1, 0, 0, 0);
            a0 = MFMA16(ah[c], Bl[0][c], a0, 0, 0, 0);
            a1 = MFMA16(ah[c], Bl[1][c], a1, 0, 0, 0);
            a0 = MFMA16(al[c], Bh[0][c], a0, 0, 0, 0);
            a1 = MFMA16(al[c], Bh[1][c], a1, 0, 0, 0);
        }
#pragma unroll
        for (int u = 0; u < 2; ++u) {
            const f32x4 av = u ? a1 : a0;
            const long pt = pbase + w * 32 + u * 16 + fr;
            float4 o = { av[0], av[1], av[2], av[3] };
            *(float4*)&out[pt * 256 + t16 * 16 + g * 4] = o;   // no relu on final layer
        }
    }
}

// ---------------------------------------------------------------------------

extern "C" void kernel_launch(void* const* d_in, const int* in_sizes, int n_in,
                              void* d_out, int out_size, void* d_ws, size_t ws_size,
                              hipStream_t stream)
{
    const float* x   = (const float*)d_in[0];
    const int*   knn = (const int*)d_in[1];
    const float* W1  = (const float*)d_in[2];
    const float* b1  = (const float*)d_in[3];
    const float* Wc0 = (const float*)d_in[4];
    const float* bc0 = (const float*)d_in[5];
    const float* Wc1 = (const float*)d_in[6];
    const float* bc1 = (const float*)d_in[7];
    const float* W2  = (const float*)d_in[8];
    const float* b2  = (const float*)d_in[9];
    float* out = (float*)d_out;

    _Float16* t = (_Float16*)d_ws;                                   // 16 MiB
    unsigned short* wb = (unsigned short*)((char*)d_ws + (size_t)65536 * 128 * 2);

    k_prep<<<dim3(256), dim3(256), 0, stream>>>(Wc0, Wc1, W2, wb);
    k_mlp <<<dim3(512), dim3(256), 0, stream>>>(x, W1, b1, bc0, bc1, wb, t);
    k_out <<<dim3(512), dim3(256), 0, stream>>>(knn, t, wb, b2, out);
}

// Round 3
// 106.381 us; speedup vs baseline: 1.6356x; 1.1214x over previous
//
#include <hip/hip_runtime.h>

// AugmentShallow, round 3: 3-kernel f16 MFMA pipeline.
//
// t[b,j] = MLP(x[b,j]) per point (k_mlp); m = mean_k gather(t) (k_gather);
// out = W2 m + b2 (k_gemm). All GEMMs on matrix cores via f16 scaled-lo
// weight split: W = Wh + 2^-12 * Wl (both f16) -> 2 MFMA chains + 1 fma.
// Activations (h1, h2, t, m) are single-plane f16 (~2^-12 rel each).
//
// k_mlp: oc-split waves (weights in registers, read once per block),
//        h ping-pong in 32 KiB LDS, 2 barriers.
// k_gather: 8 lanes cover one row contiguously -> 16 cache lines per
//        load instruction (4x fewer transactions than round 2).
// k_gemm: weights in registers, B-frags straight from global m, no LDS.
//
// ws: [0,16Mi) t f16 [65536][128]; [16Mi,32Mi) m f16 [65536][128].

typedef __attribute__((ext_vector_type(8))) _Float16 h8;
typedef __attribute__((ext_vector_type(4))) _Float16 h4;
typedef __attribute__((ext_vector_type(4))) float    f4;

#define MFMA_H __builtin_amdgcn_mfma_f32_16x16x32_f16

#define LO_SCALE_INV 2.44140625e-4f   // 2^-12

__device__ __forceinline__ void splitW8(const float* __restrict__ p, h8& hi, h8& lo) {
    const float4 a = *(const float4*)p;
    const float4 b = *(const float4*)(p + 4);
    const float v[8] = {a.x, a.y, a.z, a.w, b.x, b.y, b.z, b.w};
#pragma unroll
    for (int j = 0; j < 8; ++j) {
        const _Float16 h = (_Float16)v[j];
        hi[j] = h;
        lo[j] = (_Float16)((v[j] - (float)h) * 4096.f);
    }
}

// ---------------------------------------------------------------------------
// Kernel 1: point MLP. 1024 blocks x 256 thr, 64 points per block.
// Wave w owns oc range [32w, 32w+32) for ALL 64 points; weights in regs.
// h1 -> hA, h2 -> hB (LDS, f16, chunk^(pt&7) swizzle), h3 -> t (global f16).
// ---------------------------------------------------------------------------
__global__ __launch_bounds__(256) void k_mlp(
    const float* __restrict__ x,
    const float* __restrict__ W1, const float* __restrict__ b1,
    const float* __restrict__ Wc0, const float* __restrict__ bc0,
    const float* __restrict__ Wc1, const float* __restrict__ bc1,
    _Float16* __restrict__ t)
{
    __shared__ __align__(16) _Float16 hA[64 * 128];   // 16 KiB
    __shared__ __align__(16) _Float16 hB[64 * 128];   // 16 KiB

    const int tid = threadIdx.x;
    const int bid = blockIdx.x;
    const int lb  = (bid & 7) * 128 + (bid >> 3);   // batch = lb>>7 = bid&7 (XCD pin)
    const long pblk = (long)lb * 64;

    // ---- layer 1 (VALU, K=3, no relu): thread = (pt, 32-ch quarter) ----
    {
        const int pt  = tid >> 2;
        const int q4  = tid & 3;
        const int ch0 = q4 * 32;
        const float* xp = x + (pblk + pt) * 3;
        const float x0 = xp[0], x1 = xp[1], x2 = xp[2];
        const int p7 = pt & 7;
#pragma unroll
        for (int q = 0; q < 4; ++q) {
            h8 hv;
#pragma unroll
            for (int j = 0; j < 8; ++j) {
                const int c = ch0 + q * 8 + j;
                float v = b1[c];
                v = fmaf(W1[c * 3 + 0], x0, v);
                v = fmaf(W1[c * 3 + 1], x1, v);
                v = fmaf(W1[c * 3 + 2], x2, v);
                hv[j] = (_Float16)v;
            }
            const int chunk = q4 * 4 + q;
            *(h8*)&hA[pt * 128 + ((chunk ^ p7) << 3)] = hv;
        }
    }
    __syncthreads();

    const int lane = tid & 63;
    const int w  = tid >> 6;
    const int fr = lane & 15;
    const int g  = lane >> 4;
    const int ocb = w * 32;

#pragma unroll
    for (int layer = 0; layer < 2; ++layer) {
        const float* W  = layer ? Wc1 : Wc0;
        const float* bp = layer ? bc1 : bc0;

        h8 Ah[2][4], Al[2][4];
#pragma unroll
        for (int T = 0; T < 2; ++T)
#pragma unroll
            for (int c = 0; c < 4; ++c)
                splitW8(W + (long)(ocb + T * 16 + fr) * 128 + c * 32 + g * 8,
                        Ah[T][c], Al[T][c]);

        f4 bias[2];
#pragma unroll
        for (int T = 0; T < 2; ++T) {
            const float4 bv = *(const float4*)(bp + ocb + T * 16 + g * 4);
            bias[T] = (f4){bv.x, bv.y, bv.z, bv.w};
        }

        const _Float16* hin = layer ? hB : hA;
        const f4 zf = {0.f, 0.f, 0.f, 0.f};

#pragma unroll 2
        for (int p = 0; p < 4; ++p) {
            const int pt = p * 16 + fr;
            const int p7 = pt & 7;
            h8 B[4];
#pragma unroll
            for (int c = 0; c < 4; ++c)
                B[c] = *(const h8*)&hin[pt * 128 + (((4 * c + g) ^ p7) << 3)];

            f4 ahi[2] = {bias[0], bias[1]};
            f4 alo[2] = {zf, zf};
#pragma unroll
            for (int c = 0; c < 4; ++c) {
#pragma unroll
                for (int T = 0; T < 2; ++T) {
                    ahi[T] = MFMA_H(Ah[T][c], B[c], ahi[T], 0, 0, 0);
                    alo[T] = MFMA_H(Al[T][c], B[c], alo[T], 0, 0, 0);
                }
            }
#pragma unroll
            for (int T = 0; T < 2; ++T) {
                const int ocoff = ocb + T * 16 + g * 4;
                h4 o;
#pragma unroll
                for (int r = 0; r < 4; ++r)
                    o[r] = (_Float16)fmaxf(fmaf(alo[T][r], LO_SCALE_INV, ahi[T][r]), 0.f);
                if (layer == 0) {
                    const int sidx = pt * 128 + (((ocoff >> 3) ^ p7) << 3) + (ocoff & 7);
                    *(h4*)&hB[sidx] = o;
                } else {
                    *(h4*)&t[(pblk + pt) * 128 + ocoff] = o;
                }
            }
        }
        if (layer == 0) __syncthreads();
    }
}

// ---------------------------------------------------------------------------
// Kernel 2: gather-mean. 2048 blocks x 256 thr; thread = (pt, 8-ch oct).
// 8 lanes share a row -> each load inst touches 16 cache lines (8 rows x
// 128B contiguous). f32 accumulate, f16 store to m.
// ---------------------------------------------------------------------------
__global__ __launch_bounds__(256) void k_gather(
    const int* __restrict__ knn, const _Float16* __restrict__ t,
    _Float16* __restrict__ m)
{
    const int bid = blockIdx.x;
    const int lb  = (bid & 7) * 256 + (bid >> 3);   // batch = lb>>8 = bid&7
    const int tid = threadIdx.x;
    const long pt = (long)lb * 32 + (tid >> 3);
    const int o8  = (tid & 7) * 8;
    const long bbase = (pt >> 13) << 13;

    const int* ip = knn + pt * 12;
    int idx[12];
    *(int4*)&idx[0] = *(const int4*)(ip + 0);
    *(int4*)&idx[4] = *(const int4*)(ip + 4);
    *(int4*)&idx[8] = *(const int4*)(ip + 8);

    float acc[16];
#pragma unroll
    for (int c = 0; c < 16; ++c) acc[c] = 0.f;

#pragma unroll 4
    for (int k = 0; k < 12; ++k) {
        const _Float16* tp = t + (bbase + idx[k]) * 128;
        const h8 va = *(const h8*)(tp + o8);
        const h8 vb = *(const h8*)(tp + 64 + o8);
#pragma unroll
        for (int j = 0; j < 8; ++j) acc[j] += (float)va[j];
#pragma unroll
        for (int j = 0; j < 8; ++j) acc[8 + j] += (float)vb[j];
    }

    h8 oa, ob;
#pragma unroll
    for (int j = 0; j < 8; ++j) {
        oa[j] = (_Float16)(acc[j] * (1.f / 12.f));
        ob[j] = (_Float16)(acc[8 + j] * (1.f / 12.f));
    }
    *(h8*)&m[pt * 128 + o8]      = oa;
    *(h8*)&m[pt * 128 + 64 + o8] = ob;
}

// ---------------------------------------------------------------------------
// Kernel 3: out = W2 m + b2. 1024 blocks x 256 thr; block = (128 pts,
// 128-oc half); wave owns 32 oc, W2 frags in regs, B straight from global.
// ---------------------------------------------------------------------------
__global__ __launch_bounds__(256) void k_gemm(
    const _Float16* __restrict__ m, const float* __restrict__ W2,
    const float* __restrict__ b2, float* __restrict__ out)
{
    const int bid = blockIdx.x;
    const int lb  = (bid & 7) * 128 + (bid >> 3);   // batch = (lb>>1)>>6 = bid&7
    const int ptblk = lb >> 1;
    const int half  = lb & 1;
    const long pbase = (long)ptblk * 128;

    const int tid = threadIdx.x;
    const int lane = tid & 63;
    const int w  = tid >> 6;
    const int fr = lane & 15;
    const int g  = lane >> 4;
    const int ocb = half * 128 + w * 32;

    h8 Ah[2][4], Al[2][4];
#pragma unroll
    for (int T = 0; T < 2; ++T)
#pragma unroll
        for (int c = 0; c < 4; ++c)
            splitW8(W2 + (long)(ocb + T * 16 + fr) * 128 + c * 32 + g * 8,
                    Ah[T][c], Al[T][c]);

    f4 bias[2];
#pragma unroll
    for (int T = 0; T < 2; ++T) {
        const float4 bv = *(const float4*)(b2 + ocb + T * 16 + g * 4);
        bias[T] = (f4){bv.x, bv.y, bv.z, bv.w};
    }
    const f4 zf = {0.f, 0.f, 0.f, 0.f};

#pragma unroll 2
    for (int p = 0; p < 8; ++p) {
        const long pt = pbase + p * 16 + fr;
        h8 B[4];
#pragma unroll
        for (int c = 0; c < 4; ++c)
            B[c] = *(const h8*)&m[pt * 128 + c * 32 + g * 8];

        f4 ahi[2] = {bias[0], bias[1]};
        f4 alo[2] = {zf, zf};
#pragma unroll
        for (int c = 0; c < 4; ++c) {
#pragma unroll
            for (int T = 0; T < 2; ++T) {
                ahi[T] = MFMA_H(Ah[T][c], B[c], ahi[T], 0, 0, 0);
                alo[T] = MFMA_H(Al[T][c], B[c], alo[T], 0, 0, 0);
            }
        }
#pragma unroll
        for (int T = 0; T < 2; ++T) {
            float4 o;
            o.x = fmaf(alo[T][0], LO_SCALE_INV, ahi[T][0]);
            o.y = fmaf(alo[T][1], LO_SCALE_INV, ahi[T][1]);
            o.z = fmaf(alo[T][2], LO_SCALE_INV, ahi[T][2]);
            o.w = fmaf(alo[T][3], LO_SCALE_INV, ahi[T][3]);
            *(float4*)&out[pt * 256 + ocb + T * 16 + g * 4] = o;   // no final relu
        }
    }
}

// ---------------------------------------------------------------------------

extern "C" void kernel_launch(void* const* d_in, const int* in_sizes, int n_in,
                              void* d_out, int out_size, void* d_ws, size_t ws_size,
                              hipStream_t stream)
{
    const float* x   = (const float*)d_in[0];
    const int*   knn = (const int*)d_in[1];
    const float* W1  = (const float*)d_in[2];
    const float* b1  = (const float*)d_in[3];
    const float* Wc0 = (const float*)d_in[4];
    const float* bc0 = (const float*)d_in[5];
    const float* Wc1 = (const float*)d_in[6];
    const float* bc1 = (const float*)d_in[7];
    const float* W2  = (const float*)d_in[8];
    const float* b2  = (const float*)d_in[9];
    float* out = (float*)d_out;

    _Float16* t = (_Float16*)d_ws;                                      // 16 MiB
    _Float16* m = (_Float16*)((char*)d_ws + (size_t)16 * 1024 * 1024);  // 16 MiB

    k_mlp   <<<dim3(1024), dim3(256), 0, stream>>>(x, W1, b1, Wc0, bc0, Wc1, bc1, t);
    k_gather<<<dim3(2048), dim3(256), 0, stream>>>(knn, t, m);
    k_gemm  <<<dim3(1024), dim3(256), 0, stream>>>(m, W2, b2, out);
}

// Round 4
// 77.275 us; speedup vs baseline: 2.2517x; 1.3767x over previous
//
#include <hip/hip_runtime.h>

// AugmentShallow, round 4: 2-kernel f16 MFMA pipeline (fused gather+GEMM).
//
// k_mlp:  t[b,j] = MLP(x[b,j]) per point (unchanged from round 3).
// k_out2: m = mean_k gather(t) -> LDS -> out = W2 m + b2, fused in one block.
//         Kills the 16MB m round-trip and one launch gap; gather phase of one
//         block overlaps the write-bound GEMM phase of the next on each CU.
//
// GEMMs on matrix cores via f16 scaled-lo weight split: W = Wh + 2^-12*Wl
// (2 MFMA chains + 1 fma combine). Activations h1/h2/t/m single-plane f16.
//
// ws: [0,16Mi) t f16 [65536][128]. (m never touches global memory now.)

typedef __attribute__((ext_vector_type(8))) _Float16 h8;
typedef __attribute__((ext_vector_type(4))) _Float16 h4;
typedef __attribute__((ext_vector_type(4))) float    f4;

#define MFMA_H __builtin_amdgcn_mfma_f32_16x16x32_f16

#define LO_SCALE_INV 2.44140625e-4f   // 2^-12

__device__ __forceinline__ void splitW8(const float* __restrict__ p, h8& hi, h8& lo) {
    const float4 a = *(const float4*)p;
    const float4 b = *(const float4*)(p + 4);
    const float v[8] = {a.x, a.y, a.z, a.w, b.x, b.y, b.z, b.w};
#pragma unroll
    for (int j = 0; j < 8; ++j) {
        const _Float16 h = (_Float16)v[j];
        hi[j] = h;
        lo[j] = (_Float16)((v[j] - (float)h) * 4096.f);
    }
}

// ---------------------------------------------------------------------------
// Kernel 1: point MLP. 1024 blocks x 256 thr, 64 points per block.
// Wave w owns oc range [32w, 32w+32) for ALL 64 points; weights in regs.
// h1 -> hA, h2 -> hB (LDS, f16, chunk^(pt&7) swizzle), h3 -> t (global f16).
// ---------------------------------------------------------------------------
__global__ __launch_bounds__(256) void k_mlp(
    const float* __restrict__ x,
    const float* __restrict__ W1, const float* __restrict__ b1,
    const float* __restrict__ Wc0, const float* __restrict__ bc0,
    const float* __restrict__ Wc1, const float* __restrict__ bc1,
    _Float16* __restrict__ t)
{
    __shared__ __align__(16) _Float16 hA[64 * 128];   // 16 KiB
    __shared__ __align__(16) _Float16 hB[64 * 128];   // 16 KiB

    const int tid = threadIdx.x;
    const int bid = blockIdx.x;
    const int lb  = (bid & 7) * 128 + (bid >> 3);   // batch = lb>>7 = bid&7 (XCD pin)
    const long pblk = (long)lb * 64;

    // ---- layer 1 (VALU, K=3, no relu): thread = (pt, 32-ch quarter) ----
    {
        const int pt  = tid >> 2;
        const int q4  = tid & 3;
        const int ch0 = q4 * 32;
        const float* xp = x + (pblk + pt) * 3;
        const float x0 = xp[0], x1 = xp[1], x2 = xp[2];
        const int p7 = pt & 7;
#pragma unroll
        for (int q = 0; q < 4; ++q) {
            h8 hv;
#pragma unroll
            for (int j = 0; j < 8; ++j) {
                const int c = ch0 + q * 8 + j;
                float v = b1[c];
                v = fmaf(W1[c * 3 + 0], x0, v);
                v = fmaf(W1[c * 3 + 1], x1, v);
                v = fmaf(W1[c * 3 + 2], x2, v);
                hv[j] = (_Float16)v;
            }
            const int chunk = q4 * 4 + q;
            *(h8*)&hA[pt * 128 + ((chunk ^ p7) << 3)] = hv;
        }
    }
    __syncthreads();

    const int lane = tid & 63;
    const int w  = tid >> 6;
    const int fr = lane & 15;
    const int g  = lane >> 4;
    const int ocb = w * 32;

#pragma unroll
    for (int layer = 0; layer < 2; ++layer) {
        const float* W  = layer ? Wc1 : Wc0;
        const float* bp = layer ? bc1 : bc0;

        h8 Ah[2][4], Al[2][4];
#pragma unroll
        for (int T = 0; T < 2; ++T)
#pragma unroll
            for (int c = 0; c < 4; ++c)
                splitW8(W + (long)(ocb + T * 16 + fr) * 128 + c * 32 + g * 8,
                        Ah[T][c], Al[T][c]);

        f4 bias[2];
#pragma unroll
        for (int T = 0; T < 2; ++T) {
            const float4 bv = *(const float4*)(bp + ocb + T * 16 + g * 4);
            bias[T] = (f4){bv.x, bv.y, bv.z, bv.w};
        }

        const _Float16* hin = layer ? hB : hA;
        const f4 zf = {0.f, 0.f, 0.f, 0.f};

#pragma unroll 2
        for (int p = 0; p < 4; ++p) {
            const int pt = p * 16 + fr;
            const int p7 = pt & 7;
            h8 B[4];
#pragma unroll
            for (int c = 0; c < 4; ++c)
                B[c] = *(const h8*)&hin[pt * 128 + (((4 * c + g) ^ p7) << 3)];

            f4 ahi[2] = {bias[0], bias[1]};
            f4 alo[2] = {zf, zf};
#pragma unroll
            for (int c = 0; c < 4; ++c) {
#pragma unroll
                for (int T = 0; T < 2; ++T) {
                    ahi[T] = MFMA_H(Ah[T][c], B[c], ahi[T], 0, 0, 0);
                    alo[T] = MFMA_H(Al[T][c], B[c], alo[T], 0, 0, 0);
                }
            }
#pragma unroll
            for (int T = 0; T < 2; ++T) {
                const int ocoff = ocb + T * 16 + g * 4;
                h4 o;
#pragma unroll
                for (int r = 0; r < 4; ++r)
                    o[r] = (_Float16)fmaxf(fmaf(alo[T][r], LO_SCALE_INV, ahi[T][r]), 0.f);
                if (layer == 0) {
                    const int sidx = pt * 128 + (((ocoff >> 3) ^ p7) << 3) + (ocoff & 7);
                    *(h4*)&hB[sidx] = o;
                } else {
                    *(h4*)&t[(pblk + pt) * 128 + ocoff] = o;
                }
            }
        }
        if (layer == 0) __syncthreads();
    }
}

// ---------------------------------------------------------------------------
// Kernel 2 (fused): gather-mean -> LDS -> out = W2 m + b2.
// 512 blocks x 256 thr; block = 128 pts of one batch (bid&7 -> XCD pin).
// Gather: thread=(pt, 8-ch oct), 4 passes of 32 pts; 8 lanes cover one
// 256B t-row contiguously. GEMM: wave owns 32 oc, loops 2 oc-halves;
// W2 frags split in-register; B frags from LDS (chunk^p7 swizzle).
// ---------------------------------------------------------------------------
__global__ __launch_bounds__(256) void k_out2(
    const int* __restrict__ knn,
    const _Float16* __restrict__ t,
    const float* __restrict__ W2, const float* __restrict__ b2,
    float* __restrict__ out)
{
    __shared__ __align__(16) _Float16 mS[128 * 128];   // 32 KiB

    const int tid = threadIdx.x;
    const int bid = blockIdx.x;
    const int lb  = (bid & 7) * 64 + (bid >> 3);    // batch = lb>>6 = bid&7
    const long pbase = (long)lb * 128;
    const long bbase = (pbase >> 13) << 13;         // batch row base in t

    // ---- gather-mean into LDS ----
    {
        const int oct = tid & 7;
        const int o8  = oct * 8;
#pragma unroll 1
        for (int pass = 0; pass < 4; ++pass) {
            const int ptl = pass * 32 + (tid >> 3);
            const int* ip = knn + (pbase + ptl) * 12;
            int idx[12];
            *(int4*)&idx[0] = *(const int4*)(ip + 0);
            *(int4*)&idx[4] = *(const int4*)(ip + 4);
            *(int4*)&idx[8] = *(const int4*)(ip + 8);

            float acc[16];
#pragma unroll
            for (int c = 0; c < 16; ++c) acc[c] = 0.f;
#pragma unroll 4
            for (int k = 0; k < 12; ++k) {
                const _Float16* tp = t + (bbase + idx[k]) * 128;
                const h8 va = *(const h8*)(tp + o8);
                const h8 vb = *(const h8*)(tp + 64 + o8);
#pragma unroll
                for (int j = 0; j < 8; ++j) acc[j] += (float)va[j];
#pragma unroll
                for (int j = 0; j < 8; ++j) acc[8 + j] += (float)vb[j];
            }
            h8 oa, ob;
#pragma unroll
            for (int j = 0; j < 8; ++j) {
                oa[j] = (_Float16)(acc[j] * (1.f / 12.f));
                ob[j] = (_Float16)(acc[8 + j] * (1.f / 12.f));
            }
            const int p7 = ptl & 7;
            *(h8*)&mS[ptl * 128 + ((oct ^ p7) << 3)]       = oa;
            *(h8*)&mS[ptl * 128 + (((oct + 8) ^ p7) << 3)] = ob;
        }
    }
    __syncthreads();

    // ---- GEMM: out = W2 m + b2 ----
    const int lane = tid & 63;
    const int w  = tid >> 6;
    const int fr = lane & 15;
    const int g  = lane >> 4;
    const f4 zf = {0.f, 0.f, 0.f, 0.f};

#pragma unroll 1
    for (int half = 0; half < 2; ++half) {
        const int ocb = half * 128 + w * 32;

        h8 Ah[2][4], Al[2][4];
#pragma unroll
        for (int T = 0; T < 2; ++T)
#pragma unroll
            for (int c = 0; c < 4; ++c)
                splitW8(W2 + (long)(ocb + T * 16 + fr) * 128 + c * 32 + g * 8,
                        Ah[T][c], Al[T][c]);

        f4 bias[2];
#pragma unroll
        for (int T = 0; T < 2; ++T) {
            const float4 bv = *(const float4*)(b2 + ocb + T * 16 + g * 4);
            bias[T] = (f4){bv.x, bv.y, bv.z, bv.w};
        }

#pragma unroll 2
        for (int p = 0; p < 8; ++p) {
            const int ptl = p * 16 + fr;
            const int p7  = ptl & 7;
            h8 B[4];
#pragma unroll
            for (int c = 0; c < 4; ++c)
                B[c] = *(const h8*)&mS[ptl * 128 + (((4 * c + g) ^ p7) << 3)];

            f4 ahi[2] = {bias[0], bias[1]};
            f4 alo[2] = {zf, zf};
#pragma unroll
            for (int c = 0; c < 4; ++c) {
#pragma unroll
                for (int T = 0; T < 2; ++T) {
                    ahi[T] = MFMA_H(Ah[T][c], B[c], ahi[T], 0, 0, 0);
                    alo[T] = MFMA_H(Al[T][c], B[c], alo[T], 0, 0, 0);
                }
            }
#pragma unroll
            for (int T = 0; T < 2; ++T) {
                float4 o;
                o.x = fmaf(alo[T][0], LO_SCALE_INV, ahi[T][0]);
                o.y = fmaf(alo[T][1], LO_SCALE_INV, ahi[T][1]);
                o.z = fmaf(alo[T][2], LO_SCALE_INV, ahi[T][2]);
                o.w = fmaf(alo[T][3], LO_SCALE_INV, ahi[T][3]);
                *(float4*)&out[(pbase + ptl) * 256 + ocb + T * 16 + g * 4] = o;
            }
        }
    }
}

// ---------------------------------------------------------------------------

extern "C" void kernel_launch(void* const* d_in, const int* in_sizes, int n_in,
                              void* d_out, int out_size, void* d_ws, size_t ws_size,
                              hipStream_t stream)
{
    const float* x   = (const float*)d_in[0];
    const int*   knn = (const int*)d_in[1];
    const float* W1  = (const float*)d_in[2];
    const float* b1  = (const float*)d_in[3];
    const float* Wc0 = (const float*)d_in[4];
    const float* bc0 = (const float*)d_in[5];
    const float* Wc1 = (const float*)d_in[6];
    const float* bc1 = (const float*)d_in[7];
    const float* W2  = (const float*)d_in[8];
    const float* b2  = (const float*)d_in[9];
    float* out = (float*)d_out;

    _Float16* t = (_Float16*)d_ws;   // 16 MiB

    k_mlp <<<dim3(1024), dim3(256), 0, stream>>>(x, W1, b1, Wc0, bc0, Wc1, bc1, t);
    k_out2<<<dim3(512),  dim3(256), 0, stream>>>(knn, t, W2, b2, out);
}